// Round 5
// baseline (59.403 us; speedup 1.0000x reference)
//
#include <hip/hip_runtime.h>

#define BATCH 4096
#define CTX 10
#define NEG 20
#define DIM 128
#define NWORDS (CTX + CTX * NEG)   // 210
#define ROWS 2                     // batch rows per block
#define GPR 32                     // word-groups per row (64 groups / 2 rows)
#define NPASS 7                    // ceil(210 / 32)

__device__ __forceinline__ float log_sigmoid(float x) {
    // log(sigmoid(x)) = min(x,0) - log(1 + exp(-|x|))   (stable)
    return fminf(x, 0.0f) - __logf(1.0f + __expf(-fabsf(x)));
}

__global__ __launch_bounds__(256, 4) void sgns_partial(
    const float* __restrict__ emb_i, const float* __restrict__ emb_o,
    const int* __restrict__ iword, const int* __restrict__ owords,
    const int* __restrict__ nwords, float* __restrict__ partial)
{
    __shared__ int   s_idx[ROWS][NWORDS];
    __shared__ float s_ivec[ROWS][DIM];
    __shared__ float s_wsum[4];

    const int tid = threadIdx.x;
    const int b0  = blockIdx.x * ROWS;

    // stage both rows' ivecs (2 x 32 lanes x float4)
    if (tid < 64) {
        const int r = tid >> 5, t = tid & 31;
        const int iw = iword[b0 + r];
        *reinterpret_cast<float4*>(&s_ivec[r][4 * t]) =
            *reinterpret_cast<const float4*>(emb_i + (size_t)iw * DIM + 4 * t);
    }
    // stage 2 x 210 gather indices
    for (int k = tid; k < ROWS * NWORDS; k += 256) {
        const int r = (k >= NWORDS);
        const int j = k - NWORDS * r;
        s_idx[r][j] = (j < CTX) ? owords[(b0 + r) * CTX + j]
                                : nwords[(b0 + r) * (CTX * NEG) + (j - CTX)];
    }
    __syncthreads();

    // 4 lanes per word; groups 0..31 -> row 0, 32..63 -> row 1
    const int grp = tid >> 2;
    const int sub = tid & 3;
    const int row = grp >> 5;
    const int gl  = grp & 31;
    const float4* __restrict__ qbase =
        reinterpret_cast<const float4*>(s_ivec[row]) + sub;

    // prologue: pass-0 row chunk (8 independent float4, 64B stride)
    float4 cur[8], nxt[8];
    {
        const float4* __restrict__ rp =
            reinterpret_cast<const float4*>(emb_o + (size_t)s_idx[row][gl] * DIM) + sub;
        #pragma unroll
        for (int u = 0; u < 8; ++u) cur[u] = rp[4 * u];
    }

    float acc = 0.0f;
    #pragma unroll
    for (int p = 0; p < NPASS; ++p) {
        // issue next pass's 8 loads (tail index clamped -> unconditional, in-bounds)
        if (p < NPASS - 1) {
            int jn = gl + GPR * (p + 1);
            jn = (jn < NWORDS) ? jn : (NWORDS - 1);
            const float4* __restrict__ rn =
                reinterpret_cast<const float4*>(emb_o + (size_t)s_idx[row][jn] * DIM) + sub;
            #pragma unroll
            for (int u = 0; u < 8; ++u) nxt[u] = rn[4 * u];
        }
        // pin: prefetch must be ISSUED before the compute below (stop the
        // scheduler from sinking the loads back to their use site)
        __builtin_amdgcn_sched_barrier(0);

        float a0 = 0.f, a1 = 0.f, a2 = 0.f, a3 = 0.f;
        #pragma unroll
        for (int u = 0; u < 8; ++u) {
            const float4 qv = qbase[4 * u];   // LDS broadcast, conflict-free
            a0 = fmaf(qv.x, cur[u].x, a0);
            a1 = fmaf(qv.y, cur[u].y, a1);
            a2 = fmaf(qv.z, cur[u].z, a2);
            a3 = fmaf(qv.w, cur[u].w, a3);
        }
        float pd = (a0 + a1) + (a2 + a3);
        // 4-lane group reduce
        pd += __shfl_xor(pd, 1, 64);
        pd += __shfl_xor(pd, 2, 64);

        const int j = gl + GPR * p;
        if (j < NWORDS) {
            const float x = (j < CTX) ? pd : -pd;  // negatives: log_sigmoid(-dot)
            acc += log_sigmoid(x);                 // counted 4x; scaled 0.25 below
        }

        if (p < NPASS - 1) {
            #pragma unroll
            for (int u = 0; u < 8; ++u) cur[u] = nxt[u];  // renamed by unroll
        }
    }

    // block reduce (each word counted 4x -> scale 0.25)
    #pragma unroll
    for (int off = 32; off > 0; off >>= 1)
        acc += __shfl_xor(acc, off, 64);

    if ((tid & 63) == 0) s_wsum[tid >> 6] = acc;
    __syncthreads();
    if (tid == 0)
        partial[blockIdx.x] = 0.25f * (s_wsum[0] + s_wsum[1] + s_wsum[2] + s_wsum[3]);
}

__global__ __launch_bounds__(256) void sgns_reduce(
    const float* __restrict__ partial, float* __restrict__ out)
{
    __shared__ float s[4];
    const int tid = threadIdx.x;

    // 2048 floats = 256 threads x 2 float4, coalesced
    float acc = 0.0f;
    #pragma unroll
    for (int k = 0; k < 2; ++k) {
        const float4 v = reinterpret_cast<const float4*>(partial)[tid + 256 * k];
        acc += (v.x + v.y) + (v.z + v.w);
    }

    #pragma unroll
    for (int off = 32; off > 0; off >>= 1)
        acc += __shfl_xor(acc, off, 64);

    if ((tid & 63) == 0) s[tid >> 6] = acc;
    __syncthreads();
    if (tid == 0)
        out[0] = -(s[0] + s[1] + s[2] + s[3]) / (float)(BATCH * CTX);
}

extern "C" void kernel_launch(void* const* d_in, const int* in_sizes, int n_in,
                              void* d_out, int out_size, void* d_ws, size_t ws_size,
                              hipStream_t stream) {
    const float* emb_i  = (const float*)d_in[0];
    const float* emb_o  = (const float*)d_in[1];
    const int*   iword  = (const int*)d_in[2];
    const int*   owords = (const int*)d_in[3];
    const int*   nwords = (const int*)d_in[4];
    float* out = (float*)d_out;
    float* partial = (float*)d_ws;   // BATCH/ROWS floats = 8 KB

    sgns_partial<<<BATCH / ROWS, 256, 0, stream>>>(emb_i, emb_o, iword, owords,
                                                   nwords, partial);
    sgns_reduce<<<1, 256, 0, stream>>>(partial, out);
}

// Round 6
// 59.147 us; speedup vs baseline: 1.0043x; 1.0043x over previous
//
#include <hip/hip_runtime.h>

#define BATCH 4096
#define CTX 10
#define NEG 20
#define DIM 128
#define NWORDS (CTX + CTX * NEG)   // 210
#define GPR 32                     // word-groups per batch row
#define NPASS 7                    // ceil(210 / 32)
#define NWAVES (BATCH * GPR * 4 / 64)   // 8192 wave partials

__device__ __forceinline__ float log_sigmoid(float x) {
    // log(sigmoid(x)) = min(x,0) - log(1 + exp(-|x|))   (stable)
    return fminf(x, 0.0f) - __logf(1.0f + __expf(-fabsf(x)));
}

// Barrier-free: one 4-lane group per (row, word-slot); everything read
// directly from global (index: 1 line/group; ivec row: L1-broadcast across
// the row's 32 groups; emb_o row chunk: the gather, 64B/line optimal).
__global__ __launch_bounds__(256) void sgns_partial(
    const float* __restrict__ emb_i, const float* __restrict__ emb_o,
    const int* __restrict__ iword, const int* __restrict__ owords,
    const int* __restrict__ nwords, float* __restrict__ wsum)
{
    const int gtid = blockIdx.x * 256 + threadIdx.x;
    const int G    = gtid >> 2;       // group id
    const int sub  = gtid & 3;        // lane within group
    const int b    = G >> 5;          // batch row
    const int gl   = G & 31;          // group within row

    // this lane's ivec fragment straight from global (same row for 128
    // consecutive threads -> one 64B line per step, L1-resident)
    const int iw = iword[b];
    const float4* __restrict__ qp =
        reinterpret_cast<const float4*>(emb_i + (size_t)iw * DIM) + sub;
    float4 q[8];
    #pragma unroll
    for (int u = 0; u < 8; ++u) q[u] = qp[4 * u];

    // precompute this group's word indices (coalesced 4B reads, dup x4 lanes)
    int idx[NPASS];
    #pragma unroll
    for (int p = 0; p < NPASS; ++p) {
        const int j = gl + GPR * p;
        idx[p] = (j >= NWORDS) ? -1
               : (j < CTX)     ? owords[b * CTX + j]
                               : nwords[b * (CTX * NEG) + (j - CTX)];
    }

    float acc = 0.0f;
    #pragma unroll
    for (int p = 0; p < NPASS; ++p) {
        if (idx[p] >= 0) {
            const float4* __restrict__ rp =
                reinterpret_cast<const float4*>(emb_o + (size_t)idx[p] * DIM) + sub;
            // 8 independent float4 loads (64B stride within the row)
            float4 r[8];
            #pragma unroll
            for (int u = 0; u < 8; ++u) r[u] = rp[4 * u];
            float a0 = 0.f, a1 = 0.f, a2 = 0.f, a3 = 0.f;
            #pragma unroll
            for (int u = 0; u < 8; ++u) {
                a0 = fmaf(q[u].x, r[u].x, a0);
                a1 = fmaf(q[u].y, r[u].y, a1);
                a2 = fmaf(q[u].z, r[u].z, a2);
                a3 = fmaf(q[u].w, r[u].w, a3);
            }
            float pd = (a0 + a1) + (a2 + a3);
            // 4-lane group reduce
            pd += __shfl_xor(pd, 1, 64);
            pd += __shfl_xor(pd, 2, 64);
            const int j = gl + GPR * p;
            const float x = (j < CTX) ? pd : -pd;  // negatives: log_sigmoid(-dot)
            acc += log_sigmoid(x);                 // counted 4x; scaled at the end
        }
    }

    // wave reduce (no LDS, no barrier); lane 0 posts the wave partial
    #pragma unroll
    for (int off = 32; off > 0; off >>= 1)
        acc += __shfl_xor(acc, off, 64);
    if ((threadIdx.x & 63) == 0)
        wsum[gtid >> 6] = acc;
}

__global__ __launch_bounds__(256) void sgns_reduce(
    const float* __restrict__ wsum, float* __restrict__ out)
{
    __shared__ float s[4];
    const int tid = threadIdx.x;

    // 8192 floats = 256 threads x 8 float4, coalesced
    float acc = 0.0f;
    #pragma unroll
    for (int k = 0; k < 8; ++k) {
        const float4 v = reinterpret_cast<const float4*>(wsum)[tid + 256 * k];
        acc += (v.x + v.y) + (v.z + v.w);
    }

    #pragma unroll
    for (int off = 32; off > 0; off >>= 1)
        acc += __shfl_xor(acc, off, 64);

    if ((tid & 63) == 0) s[tid >> 6] = acc;
    __syncthreads();
    if (tid == 0)
        out[0] = -0.25f * (s[0] + s[1] + s[2] + s[3]) / (float)(BATCH * CTX);
}

extern "C" void kernel_launch(void* const* d_in, const int* in_sizes, int n_in,
                              void* d_out, int out_size, void* d_ws, size_t ws_size,
                              hipStream_t stream) {
    const float* emb_i  = (const float*)d_in[0];
    const float* emb_o  = (const float*)d_in[1];
    const int*   iword  = (const int*)d_in[2];
    const int*   owords = (const int*)d_in[3];
    const int*   nwords = (const int*)d_in[4];
    float* out  = (float*)d_out;
    float* wsum = (float*)d_ws;   // NWAVES floats = 32 KB

    sgns_partial<<<BATCH * GPR * 4 / 256, 256, 0, stream>>>(
        emb_i, emb_o, iword, owords, nwords, wsum);
    sgns_reduce<<<1, 256, 0, stream>>>(wsum, out);
}